// Round 6
// baseline (285.860 us; speedup 1.0000x reference)
//
#include <hip/hip_runtime.h>

#define RNK 32
#define VOC 32000
#define BSZ 512
#define SEQ 24

#define CHAIN_BLOCKS 512              // 1 wave/block, 1 row/block
#define RED_CHUNKS 250                // chunks per r-slab (1024 float4 each)
#define REDUCE_BLOCKS (32 * RED_CHUNKS)   // 8000
#define DEPTH 8                       // tokens in flight per chain wave (8 x 4KB LDS)

typedef const __attribute__((address_space(1))) void* as1_cvp;
typedef __attribute__((address_space(3))) void* as3_vp;

// Issue one 32x32 fp32 token matrix (4 KB) global->LDS as 4 x (64 lanes x 16B).
// LDS dest: wave-uniform base (+ implicit lane*16, linear [r][s]); global src
// per-lane: row = j*8 + lane/8 (stride VOC*RNK floats), cols (lane%8)*4..+3.
__device__ __forceinline__ void issue_matrix_load(const float* src_tok,  // core + tok*RNK
                                                  float* lds_base, int lane) {
    const int r  = lane >> 3;
    const int c0 = (lane & 7) * 4;
    #pragma unroll
    for (int j = 0; j < 4; ++j) {
        const float* src = src_tok + (size_t)(j * 8 + r) * ((size_t)VOC * RNK) + c0;
        __builtin_amdgcn_global_load_lds((as1_cvp)src, (as3_vp)(lds_base + j * 256), 16, 0, 0);
    }
}

// ---------------------------------------------------------------------------
// Single fused kernel, 64-thread (1-wave) blocks.
//  - Blocks [0, CHAIN_BLOCKS): selected-token chain, depth-8 LDS pipeline via
//    global_load_lds + counted vmcnt (literal immediates, never 0 until tail).
//  - Blocks [CHAIN_BLOCKS, ...): stream 16KB of core each; register-only
//    butterfly reduce; lanes 0-7 do the 32 gm atomics. Last block (atomic
//    counter handshake, release/acquire via __threadfence) computes z.
// ---------------------------------------------------------------------------
__global__ __launch_bounds__(64) void fused_kernel(const float* __restrict__ core,
                                                   const int* __restrict__ y,
                                                   const float* __restrict__ alpha,
                                                   const float* __restrict__ beta,
                                                   float* __restrict__ out,
                                                   float* __restrict__ gm,
                                                   unsigned* __restrict__ counter) {
    __shared__ float mbuf[DEPTH * 1024];      // 32 KB (chain role only)

    const int tid = threadIdx.x;              // == lane (1 wave/block)

    if (blockIdx.x < CHAIN_BLOCKS) {
        // ---------------- chain role: p_tilde[row] ----------------
        const int lane = tid;
        const int s    = lane & 31;
        const int half = lane >> 5;           // 0: rows 0..15, 1: rows 16..31
        const int row  = blockIdx.x;

        int   ytok  = (lane < SEQ) ? y[row * SEQ + lane] : 0;
        float state = alpha[s];               // replicated in both halves
        float betav = beta[s];

        // Drain the scalar-ish loads above so vmcnt counts ONLY gl_lds ops.
        asm volatile("s_waitcnt vmcnt(0)" ::: "memory");

        // prologue: tokens 0..7 in flight (32 outstanding gl_lds)
        #pragma unroll
        for (int pt = 0; pt < DEPTH; ++pt) {
            const int tok = __shfl(ytok, pt, 64);
            issue_matrix_load(core + (size_t)tok * RNK, mbuf + pt * 1024, lane);
        }

        #pragma unroll
        for (int t = 0; t < SEQ; ++t) {       // fully unrolled -> waits are literals
            // token t's 4 loads retire; up to DEPTH-1 tokens stay in flight
            if      (t <= SEQ - DEPTH) asm volatile("s_waitcnt vmcnt(28)" ::: "memory");
            else if (t == SEQ - 7)     asm volatile("s_waitcnt vmcnt(24)" ::: "memory");
            else if (t == SEQ - 6)     asm volatile("s_waitcnt vmcnt(20)" ::: "memory");
            else if (t == SEQ - 5)     asm volatile("s_waitcnt vmcnt(16)" ::: "memory");
            else if (t == SEQ - 4)     asm volatile("s_waitcnt vmcnt(12)" ::: "memory");
            else if (t == SEQ - 3)     asm volatile("s_waitcnt vmcnt(8)"  ::: "memory");
            else if (t == SEQ - 2)     asm volatile("s_waitcnt vmcnt(4)"  ::: "memory");
            else                       asm volatile("s_waitcnt vmcnt(0)"  ::: "memory");
            __builtin_amdgcn_sched_barrier(0);

            if (t + DEPTH < SEQ) {            // refill the buffer just freed
                const int tok = __shfl(ytok, t + DEPTH, 64);
                issue_matrix_load(core + (size_t)tok * RNK,
                                  mbuf + ((t + DEPTH) % DEPTH) * 1024, lane);
            }

            const float* M = mbuf + (t % DEPTH) * 1024;   // bank = s -> 2-way (free)
            float a0 = 0.f, a1 = 0.f, a2 = 0.f, a3 = 0.f;
            #pragma unroll
            for (int i = 0; i < 16; i += 4) {
                a0 = fmaf(__shfl(state, half * 16 + i + 0, 64), M[(half * 16 + i + 0) * 32 + s], a0);
                a1 = fmaf(__shfl(state, half * 16 + i + 1, 64), M[(half * 16 + i + 1) * 32 + s], a1);
                a2 = fmaf(__shfl(state, half * 16 + i + 2, 64), M[(half * 16 + i + 2) * 32 + s], a2);
                a3 = fmaf(__shfl(state, half * 16 + i + 3, 64), M[(half * 16 + i + 3) * 32 + s], a3);
            }
            const float acc = (a0 + a1) + (a2 + a3);
            state = acc + __shfl_xor(acc, 32, 64);        // combine halves, re-replicate
        }

        float p = state * betav;
        #pragma unroll
        for (int m = 16; m >= 1; m >>= 1) p += __shfl_xor(p, m, 64);  // within-half sum
        if (lane == 0) out[row] = p;
    } else {
        // ---------------- reduce role: gm[r][s] += sum_v core[r][v][s] ----------------
        const int bid   = blockIdx.x - CHAIN_BLOCKS;
        const int r     = bid & 31;
        const int chunk = bid >> 5;           // 0..249

        const float4* slab = (const float4*)(core + (size_t)r * VOC * RNK);
        const int base = chunk * 1024 + tid;  // float4 index; 16 KB per block

        float a0 = 0.f, a1 = 0.f, a2 = 0.f, a3 = 0.f;
        #pragma unroll
        for (int i = 0; i < 16; ++i) {
            float4 v = slab[base + i * 64];
            a0 += v.x; a1 += v.y; a2 += v.z; a3 += v.w;
        }

        // s-phase (tid*4)%32 = (tid&7)*4 is invariant under xor 8/16/32:
        // butterfly-combine the 8 lanes sharing each phase. Register-only.
        #pragma unroll
        for (int mask = 8; mask <= 32; mask <<= 1) {
            a0 += __shfl_xor(a0, mask, 64);
            a1 += __shfl_xor(a1, mask, 64);
            a2 += __shfl_xor(a2, mask, 64);
            a3 += __shfl_xor(a3, mask, 64);
        }
        if (tid < 8) {
            const int s0 = tid * 4;
            atomicAdd(&gm[r * RNK + s0 + 0], a0);
            atomicAdd(&gm[r * RNK + s0 + 1], a1);
            atomicAdd(&gm[r * RNK + s0 + 2], a2);
            atomicAdd(&gm[r * RNK + s0 + 3], a3);
        }

        // -------- last-block-out computes z (release/acquire handshake) --------
        __threadfence();                      // release: gm atomics device-visible
        int old = 0;
        if (tid == 0) old = (int)atomicAdd(counter, 1u);
        old = __shfl(old, 0, 64);

        if (old == REDUCE_BLOCKS - 1) {
            __threadfence();                  // acquire
            const int s    = tid & 31;
            const int half = tid >> 5;

            float col[16];                    // this lane's half-column of m
            #pragma unroll
            for (int i = 0; i < 16; ++i)
                col[i] = __hip_atomic_load(&gm[(half * 16 + i) * RNK + s],
                                           __ATOMIC_RELAXED, __HIP_MEMORY_SCOPE_AGENT);

            float v = alpha[s];
            #pragma unroll
            for (int t = 0; t < SEQ; ++t) {
                float b0 = 0.f, b1 = 0.f, b2 = 0.f, b3 = 0.f;
                #pragma unroll
                for (int i = 0; i < 16; i += 4) {
                    b0 = fmaf(__shfl(v, half * 16 + i + 0, 64), col[i + 0], b0);
                    b1 = fmaf(__shfl(v, half * 16 + i + 1, 64), col[i + 1], b1);
                    b2 = fmaf(__shfl(v, half * 16 + i + 2, 64), col[i + 2], b2);
                    b3 = fmaf(__shfl(v, half * 16 + i + 3, 64), col[i + 3], b3);
                }
                const float acc = (b0 + b1) + (b2 + b3);
                v = acc + __shfl_xor(acc, 32, 64);
            }
            float z = v * beta[s];
            #pragma unroll
            for (int m = 16; m >= 1; m >>= 1) z += __shfl_xor(z, m, 64);
            if (tid == 0) out[BSZ] = z * (float)BSZ;
        }
    }
}

extern "C" void kernel_launch(void* const* d_in, const int* in_sizes, int n_in,
                              void* d_out, int out_size, void* d_ws, size_t ws_size,
                              hipStream_t stream) {
    const int*   y     = (const int*)d_in[0];
    const float* alpha = (const float*)d_in[1];
    const float* beta  = (const float*)d_in[2];
    const float* core  = (const float*)d_in[3];
    float* out = (float*)d_out;
    float* gm  = (float*)d_ws;                          // 1024 floats
    unsigned* counter = (unsigned*)(gm + RNK * RNK);    // 1 uint after gm

    hipMemsetAsync(d_ws, 0, RNK * RNK * sizeof(float) + sizeof(unsigned), stream);
    fused_kernel<<<CHAIN_BLOCKS + REDUCE_BLOCKS, 64, 0, stream>>>(
        core, y, alpha, beta, out, gm, counter);
}

// Round 7
// 45.643 us; speedup vs baseline: 6.2629x; 6.2629x over previous
//
#include <hip/hip_runtime.h>

#define RNK 32
#define VOC 32000
#define BSZ 512
#define SEQ 24

#define CHAIN_BLOCKS 512              // 1 wave/block, 1 row/block
#define RED_CHUNKS 125                // chunks per r-slab (2048 float4 each)
#define REDUCE_BLOCKS (32 * RED_CHUNKS)   // 4000
#define DEPTH 6                       // tokens in flight per chain wave (6 x 4KB LDS)

typedef const __attribute__((address_space(1))) void* as1_cvp;
typedef __attribute__((address_space(3))) void* as3_vp;

// Issue one 32x32 fp32 token matrix (4 KB) global->LDS as 4 x (64 lanes x 16B).
// LDS dest: wave-uniform base (+ implicit lane*16, linear [r][s]); global src
// per-lane: row = j*8 + lane/8 (stride VOC*RNK floats), cols (lane%8)*4..+3.
__device__ __forceinline__ void issue_matrix_load(const float* src_tok,  // core + tok*RNK
                                                  float* lds_base, int lane) {
    const int r  = lane >> 3;
    const int c0 = (lane & 7) * 4;
    #pragma unroll
    for (int j = 0; j < 4; ++j) {
        const float* src = src_tok + (size_t)(j * 8 + r) * ((size_t)VOC * RNK) + c0;
        __builtin_amdgcn_global_load_lds((as1_cvp)src, (as3_vp)(lds_base + j * 256), 16, 0, 0);
    }
}

// ---------------------------------------------------------------------------
// Fused kernel, 64-thread (1-wave) blocks, 24 KB LDS -> 6 blocks/CU.
//  - Blocks [0, CHAIN_BLOCKS): selected-token chain, depth-6 LDS pipeline via
//    global_load_lds + counted vmcnt (literals, never 0 until the tail).
//  - Blocks [CHAIN_BLOCKS, ...): stream 32 float4/thread of core; register
//    butterfly reduce; lanes 0-7 issue the 32 gm atomics. NO fences.
// ---------------------------------------------------------------------------
__global__ __launch_bounds__(64) void fused_kernel(const float* __restrict__ core,
                                                   const int* __restrict__ y,
                                                   const float* __restrict__ alpha,
                                                   const float* __restrict__ beta,
                                                   float* __restrict__ out,
                                                   float* __restrict__ gm) {
    __shared__ float mbuf[DEPTH * 1024];      // 24 KB (chain role only)

    const int tid = threadIdx.x;              // == lane (1 wave/block)

    if (blockIdx.x < CHAIN_BLOCKS) {
        // ---------------- chain role: p_tilde[row] ----------------
        const int lane = tid;
        const int s    = lane & 31;
        const int half = lane >> 5;           // 0: rows 0..15, 1: rows 16..31
        const int row  = blockIdx.x;

        int   ytok  = (lane < SEQ) ? y[row * SEQ + lane] : 0;
        float state = alpha[s];               // replicated in both halves
        float betav = beta[s];

        // Drain the loads above so vmcnt counts ONLY our gl_lds ops.
        asm volatile("s_waitcnt vmcnt(0)" ::: "memory");

        // prologue: tokens 0..5 in flight (24 outstanding gl_lds)
        #pragma unroll
        for (int pt = 0; pt < DEPTH; ++pt) {
            const int tok = __shfl(ytok, pt, 64);
            issue_matrix_load(core + (size_t)tok * RNK, mbuf + pt * 1024, lane);
        }

        #pragma unroll
        for (int t = 0; t < SEQ; ++t) {       // fully unrolled -> waits are literals
            // token t's 4 loads retire; up to DEPTH-1 tokens stay in flight
            if      (t <= SEQ - 6) asm volatile("s_waitcnt vmcnt(20)" ::: "memory");
            else if (t == SEQ - 5) asm volatile("s_waitcnt vmcnt(16)" ::: "memory");
            else if (t == SEQ - 4) asm volatile("s_waitcnt vmcnt(12)" ::: "memory");
            else if (t == SEQ - 3) asm volatile("s_waitcnt vmcnt(8)"  ::: "memory");
            else if (t == SEQ - 2) asm volatile("s_waitcnt vmcnt(4)"  ::: "memory");
            else                   asm volatile("s_waitcnt vmcnt(0)"  ::: "memory");
            __builtin_amdgcn_sched_barrier(0);

            if (t + DEPTH < SEQ) {            // refill the buffer just freed
                const int tok = __shfl(ytok, t + DEPTH, 64);
                issue_matrix_load(core + (size_t)tok * RNK,
                                  mbuf + ((t + DEPTH) % DEPTH) * 1024, lane);
            }

            const float* M = mbuf + (t % DEPTH) * 1024;   // bank = s -> 2-way (free)
            float a0 = 0.f, a1 = 0.f, a2 = 0.f, a3 = 0.f;
            #pragma unroll
            for (int i = 0; i < 16; i += 4) {
                a0 = fmaf(__shfl(state, half * 16 + i + 0, 64), M[(half * 16 + i + 0) * 32 + s], a0);
                a1 = fmaf(__shfl(state, half * 16 + i + 1, 64), M[(half * 16 + i + 1) * 32 + s], a1);
                a2 = fmaf(__shfl(state, half * 16 + i + 2, 64), M[(half * 16 + i + 2) * 32 + s], a2);
                a3 = fmaf(__shfl(state, half * 16 + i + 3, 64), M[(half * 16 + i + 3) * 32 + s], a3);
            }
            const float acc = (a0 + a1) + (a2 + a3);
            state = acc + __shfl_xor(acc, 32, 64);        // combine halves, re-replicate
        }

        float p = state * betav;
        #pragma unroll
        for (int m = 16; m >= 1; m >>= 1) p += __shfl_xor(p, m, 64);  // within-half sum
        if (lane == 0) out[row] = p;
    } else {
        // ---------------- reduce role: gm[r][s] += sum_v core[r][v][s] ----------------
        const int bid   = blockIdx.x - CHAIN_BLOCKS;
        const int r     = bid & 31;
        const int chunk = bid >> 5;           // 0..124

        const float4* slab = (const float4*)(core + (size_t)r * VOC * RNK);
        const int base = chunk * 2048 + tid;  // float4 index; 32 KB per block

        float a0 = 0.f, a1 = 0.f, a2 = 0.f, a3 = 0.f;
        #pragma unroll
        for (int i = 0; i < 32; ++i) {        // deep ILP: 32 x 1KB wave-loads in flight
            float4 v = slab[base + i * 64];
            a0 += v.x; a1 += v.y; a2 += v.z; a3 += v.w;
        }

        // s-phase (tid*4)%32 = (tid&7)*4 is invariant under xor 8/16/32:
        // butterfly-combine the 8 lanes sharing each phase. Register-only.
        #pragma unroll
        for (int mask = 8; mask <= 32; mask <<= 1) {
            a0 += __shfl_xor(a0, mask, 64);
            a1 += __shfl_xor(a1, mask, 64);
            a2 += __shfl_xor(a2, mask, 64);
            a3 += __shfl_xor(a3, mask, 64);
        }
        if (tid < 8) {                        // 125 serialized adds/address -> ~1 us, hidden
            const int s0 = tid * 4;
            atomicAdd(&gm[r * RNK + s0 + 0], a0);
            atomicAdd(&gm[r * RNK + s0 + 1], a1);
            atomicAdd(&gm[r * RNK + s0 + 2], a2);
            atomicAdd(&gm[r * RNK + s0 + 3], a3);
        }
    }
}

// ---------------------------------------------------------------------------
// z = alpha @ m^SEQ @ beta * BSZ  (single wave; runs after fused kernel)
// ---------------------------------------------------------------------------
__global__ void zchain_kernel(const float* __restrict__ gm,
                              const float* __restrict__ alpha,
                              const float* __restrict__ beta,
                              float* __restrict__ out) {
    const int lane = threadIdx.x & 63;
    const int s    = lane & 31;
    const int half = lane >> 5;

    float col[16];                            // this lane's half-column of m
    #pragma unroll
    for (int i = 0; i < 16; ++i) col[i] = gm[(half * 16 + i) * RNK + s];

    float v = alpha[s];
    #pragma unroll
    for (int t = 0; t < SEQ; ++t) {
        float a0 = 0.f, a1 = 0.f, a2 = 0.f, a3 = 0.f;
        #pragma unroll
        for (int i = 0; i < 16; i += 4) {
            a0 = fmaf(__shfl(v, half * 16 + i + 0, 64), col[i + 0], a0);
            a1 = fmaf(__shfl(v, half * 16 + i + 1, 64), col[i + 1], a1);
            a2 = fmaf(__shfl(v, half * 16 + i + 2, 64), col[i + 2], a2);
            a3 = fmaf(__shfl(v, half * 16 + i + 3, 64), col[i + 3], a3);
        }
        const float acc = (a0 + a1) + (a2 + a3);
        v = acc + __shfl_xor(acc, 32, 64);
    }
    float z = v * beta[s];
    #pragma unroll
    for (int m = 16; m >= 1; m >>= 1) z += __shfl_xor(z, m, 64);
    if (lane == 0) out[BSZ] = z * (float)BSZ;
}

extern "C" void kernel_launch(void* const* d_in, const int* in_sizes, int n_in,
                              void* d_out, int out_size, void* d_ws, size_t ws_size,
                              hipStream_t stream) {
    const int*   y     = (const int*)d_in[0];
    const float* alpha = (const float*)d_in[1];
    const float* beta  = (const float*)d_in[2];
    const float* core  = (const float*)d_in[3];
    float* out = (float*)d_out;
    float* gm  = (float*)d_ws;                // 1024 floats of scratch

    hipMemsetAsync(gm, 0, RNK * RNK * sizeof(float), stream);
    fused_kernel<<<CHAIN_BLOCKS + REDUCE_BLOCKS, 64, 0, stream>>>(core, y, alpha, beta, out, gm);
    zchain_kernel<<<1, 64, 0, stream>>>(gm, alpha, beta, out);
}